// Round 13
// baseline (338.939 us; speedup 1.0000x reference)
//
#include <hip/hip_runtime.h>

// ---------------------------------------------------------------------------
// Mamba2 layer forward, MI355X (gfx950).
// Sizes: H=2048 DI=4096 N=128 NH=64 P=64 K=4 CH=256 L=4096
// conv_dim = 4352; W_in rows padded 4416 -> 4608
// ---------------------------------------------------------------------------

typedef __bf16 bf16;
typedef __bf16 bf16x8 __attribute__((ext_vector_type(8)));
typedef __bf16 bf16x4 __attribute__((ext_vector_type(4)));
typedef float  f32x4  __attribute__((ext_vector_type(4)));

#define DEV static __device__ __forceinline__

DEV f32x4 mfma16(bf16x8 a, bf16x8 b, f32x4 c) {
  return __builtin_amdgcn_mfma_f32_16x16x32_bf16(a, b, c, 0, 0, 0);
}

DEV void gll16(const bf16* g, bf16* l) {
  __builtin_amdgcn_global_load_lds(
      (const __attribute__((address_space(1))) unsigned int*)g,
      (__attribute__((address_space(3))) unsigned int*)l, 16, 0, 0);
}

#define BAR()   asm volatile("s_barrier" ::: "memory")
#define VMW(n)  asm volatile("s_waitcnt vmcnt(" #n ")" ::: "memory")

// ---------------------------------------------------------------------------
// m97-geometry GEMM, B-transposed: C = A[M][K]*B[N][K]^T (bf16 C).
// BM=BN=128, BK=32, 4 waves (wave tile 64x64), ring-2 LDS 32KB =>
// ~4 blocks/CU co-resident: FOUR independent small barrier domains per CU
// (m97/m114 stall-interleaving regime; r1's version of this geometry was
// crippled by 9.2M bank conflicts + f32 C, both fixed here).
// Sync (r6-proven): stage(t+1) at loop top into slot s^1 (its readers were
// tile t-1, done before the prior VMW(0)+BAR); compute tile t; own-drain
// VMW(0) BEFORE the single barrier (per-wave drain + publish = cross-wave
// LDS completeness). Involution swizzle col ^= ((row>>1)&3)<<4 on 64B rows
// (pre-swizzled global src + swizzled ds_read; 0 conflicts, r7-r12).
// Split-K via blockIdx.y (bf16 partials C0/C1). DTC: f32 dt cols 4352..4415.
// ---------------------------------------------------------------------------
template <int NT, int LD, bool DTC>
__global__ __launch_bounds__(256, 4) void gemm_kernel(
    const bf16* __restrict__ Abase, const bf16* __restrict__ Bbase,
    bf16* __restrict__ C0, bf16* __restrict__ C1, float* __restrict__ dtf,
    int ldc, int ntN) {
  __shared__ __align__(16) bf16 lds[2 * 8192];  // slot: A 8KB | B 8KB
  const int tid = threadIdx.x;
  const int wid = tid >> 6, lane = tid & 63;
  const int lrow = lane & 15;
  const int lc = lane >> 4;  // 16B k-slot 0..3
  const int wm = wid & 1, wn = wid >> 1;
  const int bx = blockIdx.x / ntN, by = blockIdx.x % ntN;
  const int row0 = bx * 128, col0 = by * 128;
  const bf16* A = Abase + (size_t)blockIdx.y * (NT * 32);
  const bf16* B = Bbase + (size_t)blockIdx.y * (NT * 32);

  // stager source mapping (involution of linear LDS dest); 4 gll16/thread
  const bf16* gsrc[4];
#pragma unroll
  for (int q = 0; q < 4; ++q) {
    int P = q * 4096 + tid * 16;     // byte in 16KB slot
    int r = P >> 6;                  // 0..255: rows 0..127 = A, 128..255 = B
    int rloc = r & 127;
    int c = (P & 63) ^ (((rloc >> 1) & 3) << 4);
    gsrc[q] = (r < 128) ? A + (size_t)(row0 + rloc) * LD + (c >> 1)
                        : B + (size_t)(col0 + rloc) * LD + (c >> 1);
  }
  auto stage = [&](int s, int ko) {
    bf16* sl = lds + s * 8192;
#pragma unroll
    for (int q = 0; q < 4; ++q) gll16(gsrc[q] + ko, sl + q * 2048 + tid * 8);
  };
  auto rdA = [&](int s, int m) -> bf16x8 {
    int row = wm * 64 + m * 16 + lrow;
    int off = row * 64 + ((lc ^ ((row >> 1) & 3)) << 4);
    return *(const bf16x8*)((const char*)lds + s * 16384 + off);
  };
  auto rdB = [&](int s, int n) -> bf16x8 {
    int row = wn * 64 + n * 16 + lrow;
    int off = row * 64 + ((lc ^ ((row >> 1) & 3)) << 4);
    return *(const bf16x8*)((const char*)lds + s * 16384 + 8192 + off);
  };

  f32x4 acc[4][4] = {};
  // prologue: tile 0 fully landed, then publish
  stage(0, 0);
  VMW(0);
  BAR();
  for (int t = 0; t < NT; ++t) {
    const int s = t & 1;
    if (t + 1 < NT) stage(s ^ 1, (t + 1) * 32);  // lands under this compute
    bf16x8 b0 = rdB(s, 0), b1 = rdB(s, 1), b2 = rdB(s, 2), b3 = rdB(s, 3);
#pragma unroll
    for (int m = 0; m < 4; ++m) {
      bf16x8 a = rdA(s, m);
      acc[m][0] = mfma16(a, b0, acc[m][0]);
      acc[m][1] = mfma16(a, b1, acc[m][1]);
      acc[m][2] = mfma16(a, b2, acc[m][2]);
      acc[m][3] = mfma16(a, b3, acc[m][3]);
    }
    if (t + 1 < NT) {
      VMW(0);  // own-drain BEFORE barrier (r6-proven; r5's bug was after)
      BAR();
    }
  }
  // epilogue: bf16 C write (+ optional f32 dt side-channel)
  bf16* C = blockIdx.y ? C1 : C0;
  const int orow = lc * 4;
#pragma unroll
  for (int m = 0; m < 4; ++m)
#pragma unroll
    for (int n = 0; n < 4; ++n)
#pragma unroll
      for (int i = 0; i < 4; ++i) {
        int r = row0 + wm * 64 + m * 16 + orow + i;
        int c = col0 + wn * 64 + n * 16 + lrow;
        C[(size_t)r * ldc + c] = (bf16)acc[m][n][i];
      }
  if (DTC && by == 34 && wn == 0) {
#pragma unroll
    for (int m = 0; m < 4; ++m)
#pragma unroll
      for (int n = 0; n < 4; ++n)
#pragma unroll
        for (int i = 0; i < 4; ++i) {
          int r = row0 + wm * 64 + m * 16 + orow + i;
          int h = n * 16 + lrow;  // cols 4352..4415
          dtf[(size_t)r * 64 + h] = acc[m][n][i];
        }
  }
}

// ---------------------------------------------------------------------------
// out = (float)a + (float)b   (bf16 partials -> f32 final)
// ---------------------------------------------------------------------------
__global__ __launch_bounds__(256) void add2b_kernel(
    const bf16* __restrict__ a, const bf16* __restrict__ b,
    float* __restrict__ o, long n8) {
  long i = (long)blockIdx.x * blockDim.x + threadIdx.x;
  long stride = (long)gridDim.x * blockDim.x;
  for (; i < n8; i += stride) {
    bf16x8 va = ((const bf16x8*)a)[i];
    bf16x8 vb = ((const bf16x8*)b)[i];
    float4 o0, o1;
    o0.x = (float)va[0] + (float)vb[0];
    o0.y = (float)va[1] + (float)vb[1];
    o0.z = (float)va[2] + (float)vb[2];
    o0.w = (float)va[3] + (float)vb[3];
    o1.x = (float)va[4] + (float)vb[4];
    o1.y = (float)va[5] + (float)vb[5];
    o1.z = (float)va[6] + (float)vb[6];
    o1.w = (float)va[7] + (float)vb[7];
    ((float4*)o)[i * 2] = o0;
    ((float4*)o)[i * 2 + 1] = o1;
  }
}

// ---------------------------------------------------------------------------
// Fused casts: x->xb, W_in->winb (padded), W_out->woutb (one launch)
// ---------------------------------------------------------------------------
__global__ __launch_bounds__(256) void cast_all_kernel(
    const float* __restrict__ x, bf16* __restrict__ xb,
    const float* __restrict__ W_in, bf16* __restrict__ winb,
    const float* __restrict__ W_out, bf16* __restrict__ woutb) {
  const long stride = (long)gridDim.x * blockDim.x;
  const long base = (long)blockIdx.x * blockDim.x + threadIdx.x;
  const long nx = (long)4096 * 2048 / 4;
  for (long i = base; i < nx; i += stride) {
    float4 v = ((const float4*)x)[i];
    ((bf16x4*)xb)[i] = bf16x4{(bf16)v.x, (bf16)v.y, (bf16)v.z, (bf16)v.w};
  }
  const long nw = (long)4608 * 2048 / 4;
  const long nwv = (long)4416 * 2048 / 4;
  for (long i = base; i < nw; i += stride) {
    bf16x4 o = {(bf16)0.f, (bf16)0.f, (bf16)0.f, (bf16)0.f};
    if (i < nwv) {
      float4 v = ((const float4*)W_in)[i];
      o = bf16x4{(bf16)v.x, (bf16)v.y, (bf16)v.z, (bf16)v.w};
    }
    ((bf16x4*)winb)[i] = o;
  }
  const long no = (long)2048 * 4096 / 4;
  for (long i = base; i < no; i += stride) {
    float4 v = ((const float4*)W_out)[i];
    ((bf16x4*)woutb)[i] = bf16x4{(bf16)v.x, (bf16)v.y, (bf16)v.z, (bf16)v.w};
  }
}

// ---------------------------------------------------------------------------
// dt/cumsum from f32 dt side-channel
// ---------------------------------------------------------------------------
__global__ __launch_bounds__(256) void dt_scan_kernel(
    const float* __restrict__ dtf, const float* __restrict__ dt_bias,
    const float* __restrict__ A_log, float* __restrict__ dt,
    float* __restrict__ Acs, float* __restrict__ decayO,
    float* __restrict__ expAcs, float* __restrict__ csum) {
  const int c = blockIdx.x, h = blockIdx.y;
  const int k = threadIdx.x;
  const int t = c * 256 + k;
  __shared__ float buf[256];
  float raw = dtf[(size_t)t * 64 + h] + dt_bias[h];
  float dtv = raw > 20.f ? raw : log1pf(__expf(raw));
  dtv = fminf(fmaxf(dtv, 0.001f), 100.f);
  dt[(size_t)t * 64 + h] = dtv;
  float dA = -__expf(A_log[h]) * dtv;
  buf[k] = dA;
  __syncthreads();
  for (int off = 1; off < 256; off <<= 1) {
    float add = (k >= off) ? buf[k - off] : 0.f;
    __syncthreads();
    buf[k] += add;
    __syncthreads();
  }
  float v = buf[k];
  float total = buf[255];
  size_t base = (size_t)(c * 64 + h) * 256 + k;
  Acs[base] = v;
  expAcs[base] = __expf(v);
  decayO[base] = __expf(total - v);
  if (k == 0) csum[c * 64 + h] = total;
}

// ---------------------------------------------------------------------------
// Depthwise causal conv (K=4) + bias + SiLU; input bf16 xBC (stride 4608)
// ---------------------------------------------------------------------------
__global__ __launch_bounds__(256) void conv_kernel(
    const bf16* __restrict__ xbc, const float* __restrict__ conv_w,
    const float* __restrict__ conv_b, const float* __restrict__ dt,
    bf16* __restrict__ XS, bf16* __restrict__ XDT_T, bf16* __restrict__ Bm,
    bf16* __restrict__ BT, bf16* __restrict__ Cm) {
  const int t0 = blockIdx.x * 64;
  const int c0 = blockIdx.y * 64;
  __shared__ float lin[67 * 64];
  __shared__ bf16 tr[64 * 72];
  const int tid = threadIdx.x;
  for (int v = tid; v < 67 * 16; v += 256) {
    int r = v >> 4, c4 = (v & 15) * 4;
    int gt = t0 + r - 3;
    float4 f = {0.f, 0.f, 0.f, 0.f};
    if (gt >= 0) {
      bf16x4 b = *(const bf16x4*)(xbc + (size_t)gt * 4608 + c0 + c4);
      f.x = (float)b[0]; f.y = (float)b[1]; f.z = (float)b[2]; f.w = (float)b[3];
    }
    lin[r * 64 + c4 + 0] = f.x;
    lin[r * 64 + c4 + 1] = f.y;
    lin[r * 64 + c4 + 2] = f.z;
    lin[r * 64 + c4 + 3] = f.w;
  }
  __syncthreads();
  const int cl = tid & 63, tg = tid >> 6;
  const int ch = c0 + cl;
  const float w0 = conv_w[ch * 4 + 0], w1 = conv_w[ch * 4 + 1];
  const float w2 = conv_w[ch * 4 + 2], w3 = conv_w[ch * 4 + 3];
  const float bb = conv_b[ch];
  float vals[16];
  for (int j = 0; j < 16; ++j) {
    int tl = tg * 16 + j;
    float s = bb + lin[tl * 64 + cl] * w0 + lin[(tl + 1) * 64 + cl] * w1 +
              lin[(tl + 2) * 64 + cl] * w2 + lin[(tl + 3) * 64 + cl] * w3;
    vals[j] = s / (1.f + __expf(-s));
  }
  if (c0 < 4096) {
    const int hh = c0 >> 6;
    for (int j = 0; j < 16; ++j) {
      int t = t0 + tg * 16 + j;
      XS[(size_t)t * 4096 + ch] = (bf16)vals[j];
    }
    __syncthreads();
    for (int j = 0; j < 16; ++j) {
      int tl = tg * 16 + j;
      float dtv = dt[(size_t)(t0 + tl) * 64 + hh];
      tr[cl * 72 + tl] = (bf16)(vals[j] * dtv);
    }
    __syncthreads();
    int p = tid >> 2, toff = (tid & 3) * 16;
    bf16* dst = XDT_T + (size_t)(hh * 64 + p) * 4096 + t0 + toff;
    *(bf16x8*)(dst) = *(const bf16x8*)(tr + p * 72 + toff);
    *(bf16x8*)(dst + 8) = *(const bf16x8*)(tr + p * 72 + toff + 8);
  } else if (c0 < 4224) {
    const int n0 = c0 - 4096;
    for (int j = 0; j < 16; ++j) {
      int t = t0 + tg * 16 + j;
      Bm[(size_t)t * 128 + n0 + cl] = (bf16)vals[j];
    }
    __syncthreads();
    for (int j = 0; j < 16; ++j) tr[cl * 72 + tg * 16 + j] = (bf16)vals[j];
    __syncthreads();
    int p = tid >> 2, toff = (tid & 3) * 16;
    bf16* dst = BT + (size_t)(n0 + p) * 4096 + t0 + toff;
    *(bf16x8*)(dst) = *(const bf16x8*)(tr + p * 72 + toff);
    *(bf16x8*)(dst + 8) = *(const bf16x8*)(tr + p * 72 + toff + 8);
  } else {
    const int n0 = c0 - 4224;
    for (int j = 0; j < 16; ++j) {
      int t = t0 + tg * 16 + j;
      Cm[(size_t)t * 128 + n0 + cl] = (bf16)vals[j];
    }
  }
}

// ---------------------------------------------------------------------------
// G[c][k][s] (bf16) = sum_n Cm[c*256+k][n] * Bm[c*256+s][n]
// ---------------------------------------------------------------------------
__global__ __launch_bounds__(256) void gmat_kernel(
    const bf16* __restrict__ Cm, const bf16* __restrict__ Bm,
    bf16* __restrict__ G) {
  const int c = blockIdx.x, kt = blockIdx.y, st = blockIdx.z;
  const int tid = threadIdx.x;
  const int wave = tid >> 6, lane = tid & 63;
  const int lrow = lane & 15, lk = (lane >> 4) * 8;
  const int wr = (wave >> 1) * 64, wc = (wave & 1) * 64;
  f32x4 acc[4][4] = {};
  for (int kk = 0; kk < 4; ++kk) {
    bf16x8 aF[4], bF[4];
    for (int m = 0; m < 4; ++m)
      aF[m] = *(const bf16x8*)(Cm + (size_t)(c * 256 + kt * 128 + wr + m * 16 + lrow) * 128 + kk * 32 + lk);
    for (int n = 0; n < 4; ++n)
      bF[n] = *(const bf16x8*)(Bm + (size_t)(c * 256 + st * 128 + wc + n * 16 + lrow) * 128 + kk * 32 + lk);
    for (int m = 0; m < 4; ++m)
      for (int n = 0; n < 4; ++n)
        acc[m][n] = mfma16(aF[m], bF[n], acc[m][n]);
  }
  const int orow = (lane >> 4) * 4;
  for (int m = 0; m < 4; ++m)
    for (int n = 0; n < 4; ++n)
      for (int i = 0; i < 4; ++i) {
        int k = kt * 128 + wr + m * 16 + orow + i;
        int s = st * 128 + wc + n * 16 + lrow;
        G[((size_t)c * 256 + k) * 256 + s] = (bf16)acc[m][n][i];
      }
}

// ---------------------------------------------------------------------------
// states (bf16) = sum_k (xdt_T * decayO) * B_T
// ---------------------------------------------------------------------------
__global__ __launch_bounds__(256) void states_kernel(
    const bf16* __restrict__ XDT_T, const bf16* __restrict__ BT,
    const float* __restrict__ decayO, bf16* __restrict__ states) {
  const int c = blockIdx.x, h = blockIdx.y;
  __shared__ bf16 Ap[64 * 264];
  __shared__ float sDec[256];
  const int tid = threadIdx.x;
  const int wave = tid >> 6, lane = tid & 63;
  const int lrow = lane & 15, lk = (lane >> 4) * 8;
  sDec[tid] = decayO[(size_t)(c * 64 + h) * 256 + tid];
  __syncthreads();
  {
    int p = tid >> 2, kb = (tid & 3) * 64;
    const bf16* src = XDT_T + (size_t)(h * 64 + p) * 4096 + c * 256 + kb;
    for (int j = 0; j < 8; ++j) {
      bf16x8 v = *(const bf16x8*)(src + j * 8);
      bf16x8 o;
      for (int i = 0; i < 8; ++i) o[i] = (bf16)((float)v[i] * sDec[kb + j * 8 + i]);
      *(bf16x8*)(Ap + p * 264 + kb + j * 8) = o;
    }
  }
  __syncthreads();
  const int nb = wave * 32;
  f32x4 acc[4][2] = {};
  for (int kk = 0; kk < 8; ++kk) {
    bf16x8 aF[4], bF[2];
    for (int m = 0; m < 4; ++m)
      aF[m] = *(const bf16x8*)(Ap + (m * 16 + lrow) * 264 + kk * 32 + lk);
    for (int n = 0; n < 2; ++n)
      bF[n] = *(const bf16x8*)(BT + (size_t)(nb + n * 16 + lrow) * 4096 + c * 256 + kk * 32 + lk);
    for (int m = 0; m < 4; ++m)
      for (int n = 0; n < 2; ++n)
        acc[m][n] = mfma16(aF[m], bF[n], acc[m][n]);
  }
  bf16* st = states + (size_t)(c * 64 + h) * 64 * 128;
  const int orow = (lane >> 4) * 4;
  for (int m = 0; m < 4; ++m)
    for (int n = 0; n < 2; ++n)
      for (int i = 0; i < 4; ++i)
        st[(size_t)(m * 16 + orow + i) * 128 + nb + n * 16 + lrow] = (bf16)acc[m][n][i];
}

// ---------------------------------------------------------------------------
__global__ __launch_bounds__(128) void chunk_rec_kernel(
    const bf16* __restrict__ states, const float* __restrict__ csum,
    bf16* __restrict__ prev) {
  const int h = blockIdx.x, p = blockIdx.y;
  const int n = threadIdx.x;
  size_t base = (size_t)h * 64 * 128 + (size_t)p * 128 + n;
  float run = 0.f;
  for (int c = 0; c < 16; ++c) {
    size_t idx = (size_t)c * 64 * 64 * 128 + base;
    prev[idx] = (bf16)run;
    run = run * __expf(csum[c * 64 + h]) + (float)states[idx];
  }
}

// ---------------------------------------------------------------------------
// Y (bf16) = Y_off + Y_diag per (chunk, head).  (XS*D folded into rmsnorm.)
// ---------------------------------------------------------------------------
__global__ __launch_bounds__(256) void ydiag_kernel(
    const bf16* __restrict__ Cm, const bf16* __restrict__ prev,
    const bf16* __restrict__ Gb, const float* __restrict__ Acs,
    const float* __restrict__ expAcs, const bf16* __restrict__ XDT_T,
    bf16* __restrict__ Yb) {
  const int c = blockIdx.x, h = blockIdx.y;
  __shared__ float sAcs[256];
  __shared__ float sExp[256];
  __shared__ __align__(16) bf16 pv[64 * 136];
  __shared__ __align__(16) bf16 xd[64 * 264];
  const int tid = threadIdx.x;
  const int wave = tid >> 6, lane = tid & 63;
  const int lrow = lane & 15, lk = (lane >> 4) * 8;
  const int wv16 = wave * 16;
  sAcs[tid] = Acs[(size_t)(c * 64 + h) * 256 + tid];
  sExp[tid] = expAcs[(size_t)(c * 64 + h) * 256 + tid];
  {
    int r = tid >> 2, q = (tid & 3) * 32;
    const bf16* src = prev + (size_t)(c * 64 + h) * 8192 + r * 128 + q;
    bf16* dst = pv + r * 136 + q;
    for (int j = 0; j < 4; ++j)
      *(bf16x8*)(dst + j * 8) = *(const bf16x8*)(src + j * 8);
  }
  {
    int r = tid >> 2, q = (tid & 3) * 64;
    const bf16* src = XDT_T + (size_t)(h * 64 + r) * 4096 + c * 256 + q;
    bf16* dst = xd + r * 264 + q;
    for (int j = 0; j < 8; ++j)
      *(bf16x8*)(dst + j * 8) = *(const bf16x8*)(src + j * 8);
  }
  __syncthreads();
  f32x4 acc[4][4] = {};
  bf16x8 aYo[4][4];
#pragma unroll
  for (int kk = 0; kk < 4; ++kk)
#pragma unroll
    for (int m = 0; m < 4; ++m)
      aYo[kk][m] = *(const bf16x8*)(Cm + (size_t)(c * 256 + m * 64 + wv16 + lrow) * 128 + kk * 32 + lk);
#pragma unroll
  for (int kk = 0; kk < 4; ++kk) {
    bf16x8 bF[4];
#pragma unroll
    for (int n = 0; n < 4; ++n)
      bF[n] = *(const bf16x8*)(pv + (n * 16 + lrow) * 136 + kk * 32 + lk);
#pragma unroll
    for (int m = 0; m < 4; ++m)
#pragma unroll
      for (int n = 0; n < 4; ++n)
        acc[m][n] = mfma16(aYo[kk][m], bF[n], acc[m][n]);
  }
  const int orow = (lane >> 4) * 4;
#pragma unroll
  for (int m = 0; m < 4; ++m)
#pragma unroll
    for (int i = 0; i < 4; ++i) {
      float e = sExp[m * 64 + wv16 + orow + i];
      for (int n = 0; n < 4; ++n) acc[m][n][i] *= e;
    }
  const bf16* Gp = Gb + (size_t)c * 65536;
#pragma unroll
  for (int stile = 0; stile < 4; ++stile) {
    const int s0 = stile * 64;
    bf16x8 graw[2][4];
#pragma unroll
    for (int kk = 0; kk < 2; ++kk)
#pragma unroll
      for (int m = 0; m < 4; ++m)
        if (m * 64 + wv16 + 15 >= s0) {
          int row = m * 64 + wv16 + lrow;
          graw[kk][m] = *(const bf16x8*)(Gp + (size_t)row * 256 + s0 + kk * 32 + lk);
        }
    bf16x8 bF[2][4];
#pragma unroll
    for (int kk = 0; kk < 2; ++kk)
#pragma unroll
      for (int n = 0; n < 4; ++n)
        bF[kk][n] = *(const bf16x8*)(xd + (n * 16 + lrow) * 264 + s0 + kk * 32 + lk);
#pragma unroll
    for (int kk = 0; kk < 2; ++kk)
#pragma unroll
      for (int m = 0; m < 4; ++m) {
        if (m * 64 + wv16 + 15 < s0) continue;
        const int row = m * 64 + wv16 + lrow;
        const float ak = sAcs[row];
        bf16x8 af;
#pragma unroll
        for (int j = 0; j < 8; ++j) {
          int s = s0 + kk * 32 + lk + j;
          float v = (float)graw[kk][m][j] * __expf(ak - sAcs[s]);
          if (s > row) v = 0.f;
          af[j] = (bf16)v;
        }
#pragma unroll
        for (int n = 0; n < 4; ++n)
          acc[m][n] = mfma16(af, bF[kk][n], acc[m][n]);
      }
  }
#pragma unroll
  for (int m = 0; m < 4; ++m)
#pragma unroll
    for (int n = 0; n < 4; ++n)
#pragma unroll
      for (int i = 0; i < 4; ++i) {
        int t = c * 256 + m * 64 + wv16 + orow + i;
        int col = h * 64 + n * 16 + lrow;
        Yb[(size_t)t * 4096 + col] = (bf16)acc[m][n][i];
      }
}

// ---------------------------------------------------------------------------
// RMSNorm fused with + XS*D  (bf16 Y input)
// ---------------------------------------------------------------------------
__global__ __launch_bounds__(256) void rmsnorm_kernel(
    const bf16* __restrict__ Yb, const bf16* __restrict__ XS,
    const float* __restrict__ Dp, const float* __restrict__ norm_w,
    bf16* __restrict__ out) {
  const int row = blockIdx.x;
  const bf16x4* y4 = (const bf16x4*)(Yb + (size_t)row * 4096);
  const bf16x4* xs4 = (const bf16x4*)(XS + (size_t)row * 4096);
  float4 v[4];
  float ss = 0.f;
  for (int j = 0; j < 4; ++j) {
    int c4 = threadIdx.x + j * 256;
    bf16x4 yb = y4[c4];
    bf16x4 xs = xs4[c4];
    float d = Dp[(c4 * 4) >> 6];
    float4 y;
    y.x = (float)yb[0] + (float)xs[0] * d;
    y.y = (float)yb[1] + (float)xs[1] * d;
    y.z = (float)yb[2] + (float)xs[2] * d;
    y.w = (float)yb[3] + (float)xs[3] * d;
    v[j] = y;
    ss += y.x * y.x + y.y * y.y + y.z * y.z + y.w * y.w;
  }
  for (int off = 32; off; off >>= 1) ss += __shfl_down(ss, off, 64);
  __shared__ float ws[4];
  if ((threadIdx.x & 63) == 0) ws[threadIdx.x >> 6] = ss;
  __syncthreads();
  float scale = rsqrtf((ws[0] + ws[1] + ws[2] + ws[3]) / 4096.f + 1e-6f);
  for (int j = 0; j < 4; ++j) {
    int col = (threadIdx.x + j * 256) * 4;
    float4 w = *(const float4*)(norm_w + col);
    bf16x4 o = {(bf16)(v[j].x * scale * w.x), (bf16)(v[j].y * scale * w.y),
                (bf16)(v[j].z * scale * w.z), (bf16)(v[j].w * scale * w.w)};
    *(bf16x4*)(out + (size_t)row * 4096 + col) = o;
  }
}

// ---------------------------------------------------------------------------
extern "C" void kernel_launch(void* const* d_in, const int* in_sizes, int n_in,
                              void* d_out, int out_size, void* d_ws, size_t ws_size,
                              hipStream_t stream) {
  const float* x       = (const float*)d_in[0];
  const float* W_in    = (const float*)d_in[1];
  const float* conv_w  = (const float*)d_in[2];
  const float* conv_b  = (const float*)d_in[3];
  const float* dt_bias = (const float*)d_in[4];
  const float* A_log   = (const float*)d_in[5];
  const float* Dp      = (const float*)d_in[6];
  const float* norm_w  = (const float*)d_in[7];
  const float* W_out   = (const float*)d_in[8];

  size_t o = 0;
  char* base = (char*)d_ws;
  auto take = [&](size_t b) {
    char* p = base + o;
    o += (b + 255) & ~(size_t)255;
    return (void*)p;
  };
  bf16*  xb     = (bf16*)take((size_t)4096 * 2048 * 2);    // 16.8 MB
  bf16*  winb   = (bf16*)take((size_t)4608 * 2048 * 2);    // 18.9 MB
  bf16*  xbc    = (bf16*)take((size_t)4096 * 4608 * 2);    // 37.75 MB
  float* dtf    = (float*)take((size_t)4096 * 64 * 4);     // 1 MB
  float* dtg    = (float*)take((size_t)4096 * 64 * 4);
  float* Acs    = (float*)take((size_t)4096 * 64 * 4);
  float* decayO = (float*)take((size_t)4096 * 64 * 4);
  float* expA   = (float*)take((size_t)4096 * 64 * 4);
  float* csum   = (float*)take((size_t)16 * 64 * 4);
  bf16*  XS     = (bf16*)take((size_t)4096 * 4096 * 2);    // 33.6 MB
  bf16*  XDT_T  = (bf16*)take((size_t)4096 * 4096 * 2);    // 33.6 MB
  bf16*  Bm     = (bf16*)take((size_t)4096 * 128 * 2);
  bf16*  BT     = (bf16*)take((size_t)4096 * 128 * 2);
  bf16*  Cm     = (bf16*)take((size_t)4096 * 128 * 2);
  bf16*  Yb     = (bf16*)take((size_t)4096 * 4096 * 2);    // 33.6 MB
  bf16*  prev   = (bf16*)take((size_t)16 * 64 * 64 * 128 * 2);  // 16.8 MB
  bf16*  woutb  = (bf16*)take((size_t)2048 * 4096 * 2);    // 16.8 MB
  // aliases into xbc (dead after conv): Gb | states(bf16)
  bf16*  Gb     = (bf16*)((char*)xbc);                          // 2.10 MB
  bf16*  states = (bf16*)((char*)xbc + (size_t)4194304);        // 16.8 MB
  bf16*  ynorm  = xb;             // xb+winb dead after GEMM1; 33.6 <= 35.7
  bf16*  p2a    = XS;             // XS dead after rmsnorm
  bf16*  p2b    = XDT_T;          // XDT dead after ydiag

  // 1) fused casts (x, W_in padded, W_out)
  cast_all_kernel<<<2048, 256, 0, stream>>>(x, xb, W_in, winb, W_out, woutb);
  // 2) GEMM1 (no split): xbc = x @ W_in^T (bf16) + f32 dt; 1152 blocks 4.5/CU
  gemm_kernel<64, 2048, true><<<dim3(1152, 1), 256, 0, stream>>>(
      xb, winb, xbc, xbc, dtf, 4608, 36);
  // 3) dt + per-chunk cumsum
  dt_scan_kernel<<<dim3(16, 64), 256, 0, stream>>>(dtf, dt_bias, A_log, dtg,
                                                   Acs, decayO, expA, csum);
  // 4) conv + silu + layout builds
  conv_kernel<<<dim3(64, 68), 256, 0, stream>>>(xbc, conv_w, conv_b, dtg, XS,
                                                XDT_T, Bm, BT, Cm);
  // 5) G = C @ B^T per chunk (bf16; xbc now dead -> Gb/states live there)
  gmat_kernel<<<dim3(16, 2, 2), 256, 0, stream>>>(Cm, Bm, Gb);
  // 6) intra-chunk states (bf16)
  states_kernel<<<dim3(16, 64), 256, 0, stream>>>(XDT_T, BT, decayO, states);
  // 7) inter-chunk recurrence -> prev (bf16)
  chunk_rec_kernel<<<dim3(64, 64), 128, 0, stream>>>(states, csum, prev);
  // 8) Y = Y_diag + Y_off (bf16)
  ydiag_kernel<<<dim3(16, 64), 256, 0, stream>>>(Cm, prev, Gb, Acs, expA,
                                                 XDT_T, Yb);
  // 9) RMSNorm (fused + XS*D) -> bf16
  rmsnorm_kernel<<<4096, 256, 0, stream>>>(Yb, XS, Dp, norm_w, ynorm);
  // 10) GEMM2 split-K2 -> bf16 partials; 1024 blocks = 4/CU
  gemm_kernel<64, 4096, false><<<dim3(512, 2), 256, 0, stream>>>(
      ynorm, woutb, p2a, p2b, nullptr, 2048, 16);
  // 11) out = p2a + p2b (f32)
  add2b_kernel<<<2048, 256, 0, stream>>>(p2a, p2b, (float*)d_out,
                                         (long)4096 * 2048 / 8);
}

// Round 14
// 323.200 us; speedup vs baseline: 1.0487x; 1.0487x over previous
//
#include <hip/hip_runtime.h>

// ---------------------------------------------------------------------------
// Mamba2 layer forward, MI355X (gfx950).
// Sizes: H=2048 DI=4096 N=128 NH=64 P=64 K=4 CH=256 L=4096
// conv_dim = 4352; W_in rows padded 4416 -> 4608
// ---------------------------------------------------------------------------

typedef __bf16 bf16;
typedef __bf16 bf16x8 __attribute__((ext_vector_type(8)));
typedef __bf16 bf16x4 __attribute__((ext_vector_type(4)));
typedef float  f32x4  __attribute__((ext_vector_type(4)));

#define DEV static __device__ __forceinline__

DEV f32x4 mfma16(bf16x8 a, bf16x8 b, f32x4 c) {
  return __builtin_amdgcn_mfma_f32_16x16x32_bf16(a, b, c, 0, 0, 0);
}

DEV void gll16(const bf16* g, bf16* l) {
  __builtin_amdgcn_global_load_lds(
      (const __attribute__((address_space(1))) unsigned int*)g,
      (__attribute__((address_space(3))) unsigned int*)l, 16, 0, 0);
}

#define BAR()   asm volatile("s_barrier" ::: "memory")
#define VMW(n)  asm volatile("s_waitcnt vmcnt(" #n ")" ::: "memory")

// ---------------------------------------------------------------------------
// GEMM1 (r10-measured-best): C = A[M][K]*B[N][K]^T (bf16 C + f32 dt cols).
// BM=256 BN=128 BK=32, 8 waves (wave tile 64x64), ring-3 LDS (72KB) => 2
// blocks/CU. Counted-vmcnt ledger: 3 gll16/thread/tile; entry outstanding
// 6 = {t,t+1}; VMW(3) retires tile t (issued 2 iters ago => ~0 wait); BAR
// publishes; stage(t+2) into slot (t+2)%3 (readers = compute(t-1), pre-BAR).
// Tail VMW(0). Involution swizzle col ^= ((row>>1)&3)<<4 (0 conflicts).
// ---------------------------------------------------------------------------
template <int NT, int LD, bool DTC>
__global__ __launch_bounds__(512, 4) void gemm_kernel(
    const bf16* __restrict__ Abase, const bf16* __restrict__ Bbase,
    bf16* __restrict__ C0, float* __restrict__ dtf, int ldc, int ntN) {
  __shared__ __align__(16) bf16 lds[3 * 12288];  // slot: A 16KB | B 8KB
  const int tid = threadIdx.x;
  const int wid = tid >> 6, lane = tid & 63;
  const int lrow = lane & 15;
  const int lc = lane >> 4;  // 16B k-slot 0..3
  const int wm = wid & 3, wn = wid >> 2;
  const int bx = blockIdx.x / ntN, by = blockIdx.x % ntN;
  const int row0 = bx * 256, col0 = by * 128;
  const bf16* A = Abase;
  const bf16* B = Bbase;

  // stager source mapping (involution of linear LDS dest)
  const bf16* gA[2];
  const bf16* gB0;
#pragma unroll
  for (int q = 0; q < 2; ++q) {
    int P = q * 8192 + tid * 16;
    int Lq = P ^ (((P >> 7) & 3) << 4);
    int srow = Lq >> 6;          // 0..255
    int selem = (Lq & 63) >> 1;  // 0..31
    gA[q] = A + (size_t)(row0 + srow) * LD + selem;
  }
  {
    int P = tid * 16;
    int Lq = P ^ (((P >> 7) & 3) << 4);
    int srow = Lq >> 6;          // 0..127
    int selem = (Lq & 63) >> 1;
    gB0 = B + (size_t)(col0 + srow) * LD + selem;
  }
  auto stage = [&](int s, int ko) {
    bf16* sl = lds + s * 12288;
    gll16(gA[0] + ko, sl + tid * 8);
    gll16(gA[1] + ko, sl + 4096 + tid * 8);
    gll16(gB0 + ko, sl + 8192 + tid * 8);
  };
  auto rdA = [&](int s, int m) -> bf16x8 {
    int row = wm * 64 + m * 16 + lrow;
    int off = row * 64 + ((lc ^ ((row >> 1) & 3)) << 4);
    return *(const bf16x8*)((const char*)lds + s * 24576 + off);
  };
  auto rdB = [&](int s, int n) -> bf16x8 {
    int row = wn * 64 + n * 16 + lrow;
    int off = row * 64 + ((lc ^ ((row >> 1) & 3)) << 4);
    return *(const bf16x8*)((const char*)lds + s * 24576 + 16384 + off);
  };

  f32x4 acc[4][4] = {};
  // prologue: tiles 0 and 1 in flight (6 outstanding)
  stage(0, 0);
  stage(1, 32);
  int rs = 0, ws = 2;
  for (int t = 0; t < NT; ++t) {
    if (t + 1 < NT) { VMW(3); } else { VMW(0); }
    BAR();
    if (t + 2 < NT) stage(ws, (t + 2) * 32);
    bf16x8 b0 = rdB(rs, 0), b1 = rdB(rs, 1), b2 = rdB(rs, 2), b3 = rdB(rs, 3);
#pragma unroll
    for (int m = 0; m < 4; ++m) {
      bf16x8 a = rdA(rs, m);
      acc[m][0] = mfma16(a, b0, acc[m][0]);
      acc[m][1] = mfma16(a, b1, acc[m][1]);
      acc[m][2] = mfma16(a, b2, acc[m][2]);
      acc[m][3] = mfma16(a, b3, acc[m][3]);
    }
    rs = (rs == 2) ? 0 : rs + 1;
    ws = (ws == 2) ? 0 : ws + 1;
  }
  // epilogue: bf16 C write (+ optional f32 dt side-channel)
  const int orow = lc * 4;
#pragma unroll
  for (int m = 0; m < 4; ++m)
#pragma unroll
    for (int n = 0; n < 4; ++n)
#pragma unroll
      for (int i = 0; i < 4; ++i) {
        int r = row0 + wm * 64 + m * 16 + orow + i;
        int c = col0 + wn * 64 + n * 16 + lrow;
        C0[(size_t)r * ldc + c] = (bf16)acc[m][n][i];
      }
  if (DTC && by == 34 && wn == 0) {
#pragma unroll
    for (int m = 0; m < 4; ++m)
#pragma unroll
      for (int n = 0; n < 4; ++n)
#pragma unroll
        for (int i = 0; i < 4; ++i) {
          int r = row0 + wm * 64 + m * 16 + orow + i;
          int h = n * 16 + lrow;  // cols 4352..4415
          dtf[(size_t)r * 64 + h] = acc[m][n][i];
        }
  }
}

// ---------------------------------------------------------------------------
// GEMM2: 128x128 tile, no split-K (grid 32x16=512 = 2/CU), f32 C direct.
// BK=32, 4 waves (wave tile 64x64), ring-3 LDS (48KB). Counted ledger:
// 4 gll16/thread/tile; prologue 8 outstanding {t0,t1}; VMW(4) retires tile t;
// BAR publishes; stage(t+2). Tail VMW(0). Same verified swizzle.
// ---------------------------------------------------------------------------
template <int NT, int LD>
__global__ __launch_bounds__(256, 3) void gemm2_kernel(
    const bf16* __restrict__ Abase, const bf16* __restrict__ Bbase,
    float* __restrict__ C, int ldc, int ntN) {
  __shared__ __align__(16) bf16 lds[3 * 8192];  // slot: A 8KB | B 8KB
  const int tid = threadIdx.x;
  const int wid = tid >> 6, lane = tid & 63;
  const int lrow = lane & 15;
  const int lc = lane >> 4;
  const int wm = wid & 1, wn = wid >> 1;
  const int bx = blockIdx.x / ntN, by = blockIdx.x % ntN;
  const int row0 = bx * 128, col0 = by * 128;

  const bf16* gsrc[4];
#pragma unroll
  for (int q = 0; q < 4; ++q) {
    int P = q * 4096 + tid * 16;     // byte in 16KB slot
    int r = P >> 6;                  // 0..255: rows 0..127 = A, 128..255 = B
    int rloc = r & 127;
    int c = (P & 63) ^ (((rloc >> 1) & 3) << 4);
    gsrc[q] = (r < 128) ? Abase + (size_t)(row0 + rloc) * LD + (c >> 1)
                        : Bbase + (size_t)(col0 + rloc) * LD + (c >> 1);
  }
  auto stage = [&](int s, int ko) {
    bf16* sl = lds + s * 8192;
#pragma unroll
    for (int q = 0; q < 4; ++q) gll16(gsrc[q] + ko, sl + q * 2048 + tid * 8);
  };
  auto rdA = [&](int s, int m) -> bf16x8 {
    int row = wm * 64 + m * 16 + lrow;
    int off = row * 64 + ((lc ^ ((row >> 1) & 3)) << 4);
    return *(const bf16x8*)((const char*)lds + s * 16384 + off);
  };
  auto rdB = [&](int s, int n) -> bf16x8 {
    int row = wn * 64 + n * 16 + lrow;
    int off = row * 64 + ((lc ^ ((row >> 1) & 3)) << 4);
    return *(const bf16x8*)((const char*)lds + s * 16384 + 8192 + off);
  };

  f32x4 acc[4][4] = {};
  stage(0, 0);
  stage(1, 32);
  int rs = 0, ws = 2;
  for (int t = 0; t < NT; ++t) {
    if (t + 1 < NT) { VMW(4); } else { VMW(0); }
    BAR();
    if (t + 2 < NT) stage(ws, (t + 2) * 32);
    bf16x8 b0 = rdB(rs, 0), b1 = rdB(rs, 1), b2 = rdB(rs, 2), b3 = rdB(rs, 3);
#pragma unroll
    for (int m = 0; m < 4; ++m) {
      bf16x8 a = rdA(rs, m);
      acc[m][0] = mfma16(a, b0, acc[m][0]);
      acc[m][1] = mfma16(a, b1, acc[m][1]);
      acc[m][2] = mfma16(a, b2, acc[m][2]);
      acc[m][3] = mfma16(a, b3, acc[m][3]);
    }
    rs = (rs == 2) ? 0 : rs + 1;
    ws = (ws == 2) ? 0 : ws + 1;
  }
  const int orow = lc * 4;
#pragma unroll
  for (int m = 0; m < 4; ++m)
#pragma unroll
    for (int n = 0; n < 4; ++n)
#pragma unroll
      for (int i = 0; i < 4; ++i) {
        int r = row0 + wm * 64 + m * 16 + orow + i;
        int c = col0 + wn * 64 + n * 16 + lrow;
        C[(size_t)r * ldc + c] = acc[m][n][i];
      }
}

// ---------------------------------------------------------------------------
// Fused casts: x->xb, W_in->winb (padded), W_out->woutb (one launch)
// ---------------------------------------------------------------------------
__global__ __launch_bounds__(256) void cast_all_kernel(
    const float* __restrict__ x, bf16* __restrict__ xb,
    const float* __restrict__ W_in, bf16* __restrict__ winb,
    const float* __restrict__ W_out, bf16* __restrict__ woutb) {
  const long stride = (long)gridDim.x * blockDim.x;
  const long base = (long)blockIdx.x * blockDim.x + threadIdx.x;
  const long nx = (long)4096 * 2048 / 4;
  for (long i = base; i < nx; i += stride) {
    float4 v = ((const float4*)x)[i];
    ((bf16x4*)xb)[i] = bf16x4{(bf16)v.x, (bf16)v.y, (bf16)v.z, (bf16)v.w};
  }
  const long nw = (long)4608 * 2048 / 4;
  const long nwv = (long)4416 * 2048 / 4;
  for (long i = base; i < nw; i += stride) {
    bf16x4 o = {(bf16)0.f, (bf16)0.f, (bf16)0.f, (bf16)0.f};
    if (i < nwv) {
      float4 v = ((const float4*)W_in)[i];
      o = bf16x4{(bf16)v.x, (bf16)v.y, (bf16)v.z, (bf16)v.w};
    }
    ((bf16x4*)winb)[i] = o;
  }
  const long no = (long)2048 * 4096 / 4;
  for (long i = base; i < no; i += stride) {
    float4 v = ((const float4*)W_out)[i];
    ((bf16x4*)woutb)[i] = bf16x4{(bf16)v.x, (bf16)v.y, (bf16)v.z, (bf16)v.w};
  }
}

// ---------------------------------------------------------------------------
// dt/cumsum from f32 dt side-channel
// ---------------------------------------------------------------------------
__global__ __launch_bounds__(256) void dt_scan_kernel(
    const float* __restrict__ dtf, const float* __restrict__ dt_bias,
    const float* __restrict__ A_log, float* __restrict__ dt,
    float* __restrict__ Acs, float* __restrict__ decayO,
    float* __restrict__ expAcs, float* __restrict__ csum) {
  const int c = blockIdx.x, h = blockIdx.y;
  const int k = threadIdx.x;
  const int t = c * 256 + k;
  __shared__ float buf[256];
  float raw = dtf[(size_t)t * 64 + h] + dt_bias[h];
  float dtv = raw > 20.f ? raw : log1pf(__expf(raw));
  dtv = fminf(fmaxf(dtv, 0.001f), 100.f);
  dt[(size_t)t * 64 + h] = dtv;
  float dA = -__expf(A_log[h]) * dtv;
  buf[k] = dA;
  __syncthreads();
  for (int off = 1; off < 256; off <<= 1) {
    float add = (k >= off) ? buf[k - off] : 0.f;
    __syncthreads();
    buf[k] += add;
    __syncthreads();
  }
  float v = buf[k];
  float total = buf[255];
  size_t base = (size_t)(c * 64 + h) * 256 + k;
  Acs[base] = v;
  expAcs[base] = __expf(v);
  decayO[base] = __expf(total - v);
  if (k == 0) csum[c * 64 + h] = total;
}

// ---------------------------------------------------------------------------
// Depthwise causal conv (K=4) + bias + SiLU; input bf16 xBC (stride 4608)
// ---------------------------------------------------------------------------
__global__ __launch_bounds__(256) void conv_kernel(
    const bf16* __restrict__ xbc, const float* __restrict__ conv_w,
    const float* __restrict__ conv_b, const float* __restrict__ dt,
    bf16* __restrict__ XS, bf16* __restrict__ XDT_T, bf16* __restrict__ Bm,
    bf16* __restrict__ BT, bf16* __restrict__ Cm) {
  const int t0 = blockIdx.x * 64;
  const int c0 = blockIdx.y * 64;
  __shared__ float lin[67 * 64];
  __shared__ bf16 tr[64 * 72];
  const int tid = threadIdx.x;
  for (int v = tid; v < 67 * 16; v += 256) {
    int r = v >> 4, c4 = (v & 15) * 4;
    int gt = t0 + r - 3;
    float4 f = {0.f, 0.f, 0.f, 0.f};
    if (gt >= 0) {
      bf16x4 b = *(const bf16x4*)(xbc + (size_t)gt * 4608 + c0 + c4);
      f.x = (float)b[0]; f.y = (float)b[1]; f.z = (float)b[2]; f.w = (float)b[3];
    }
    lin[r * 64 + c4 + 0] = f.x;
    lin[r * 64 + c4 + 1] = f.y;
    lin[r * 64 + c4 + 2] = f.z;
    lin[r * 64 + c4 + 3] = f.w;
  }
  __syncthreads();
  const int cl = tid & 63, tg = tid >> 6;
  const int ch = c0 + cl;
  const float w0 = conv_w[ch * 4 + 0], w1 = conv_w[ch * 4 + 1];
  const float w2 = conv_w[ch * 4 + 2], w3 = conv_w[ch * 4 + 3];
  const float bb = conv_b[ch];
  float vals[16];
  for (int j = 0; j < 16; ++j) {
    int tl = tg * 16 + j;
    float s = bb + lin[tl * 64 + cl] * w0 + lin[(tl + 1) * 64 + cl] * w1 +
              lin[(tl + 2) * 64 + cl] * w2 + lin[(tl + 3) * 64 + cl] * w3;
    vals[j] = s / (1.f + __expf(-s));
  }
  if (c0 < 4096) {
    const int hh = c0 >> 6;
    for (int j = 0; j < 16; ++j) {
      int t = t0 + tg * 16 + j;
      XS[(size_t)t * 4096 + ch] = (bf16)vals[j];
    }
    __syncthreads();
    for (int j = 0; j < 16; ++j) {
      int tl = tg * 16 + j;
      float dtv = dt[(size_t)(t0 + tl) * 64 + hh];
      tr[cl * 72 + tl] = (bf16)(vals[j] * dtv);
    }
    __syncthreads();
    int p = tid >> 2, toff = (tid & 3) * 16;
    bf16* dst = XDT_T + (size_t)(hh * 64 + p) * 4096 + t0 + toff;
    *(bf16x8*)(dst) = *(const bf16x8*)(tr + p * 72 + toff);
    *(bf16x8*)(dst + 8) = *(const bf16x8*)(tr + p * 72 + toff + 8);
  } else if (c0 < 4224) {
    const int n0 = c0 - 4096;
    for (int j = 0; j < 16; ++j) {
      int t = t0 + tg * 16 + j;
      Bm[(size_t)t * 128 + n0 + cl] = (bf16)vals[j];
    }
    __syncthreads();
    for (int j = 0; j < 16; ++j) tr[cl * 72 + tg * 16 + j] = (bf16)vals[j];
    __syncthreads();
    int p = tid >> 2, toff = (tid & 3) * 16;
    bf16* dst = BT + (size_t)(n0 + p) * 4096 + t0 + toff;
    *(bf16x8*)(dst) = *(const bf16x8*)(tr + p * 72 + toff);
    *(bf16x8*)(dst + 8) = *(const bf16x8*)(tr + p * 72 + toff + 8);
  } else {
    const int n0 = c0 - 4224;
    for (int j = 0; j < 16; ++j) {
      int t = t0 + tg * 16 + j;
      Cm[(size_t)t * 128 + n0 + cl] = (bf16)vals[j];
    }
  }
}

// ---------------------------------------------------------------------------
// G[c][k][s] (bf16) = sum_n Cm[c*256+k][n] * Bm[c*256+s][n]
// ---------------------------------------------------------------------------
__global__ __launch_bounds__(256) void gmat_kernel(
    const bf16* __restrict__ Cm, const bf16* __restrict__ Bm,
    bf16* __restrict__ G) {
  const int c = blockIdx.x, kt = blockIdx.y, st = blockIdx.z;
  const int tid = threadIdx.x;
  const int wave = tid >> 6, lane = tid & 63;
  const int lrow = lane & 15, lk = (lane >> 4) * 8;
  const int wr = (wave >> 1) * 64, wc = (wave & 1) * 64;
  f32x4 acc[4][4] = {};
  for (int kk = 0; kk < 4; ++kk) {
    bf16x8 aF[4], bF[4];
    for (int m = 0; m < 4; ++m)
      aF[m] = *(const bf16x8*)(Cm + (size_t)(c * 256 + kt * 128 + wr + m * 16 + lrow) * 128 + kk * 32 + lk);
    for (int n = 0; n < 4; ++n)
      bF[n] = *(const bf16x8*)(Bm + (size_t)(c * 256 + st * 128 + wc + n * 16 + lrow) * 128 + kk * 32 + lk);
    for (int m = 0; m < 4; ++m)
      for (int n = 0; n < 4; ++n)
        acc[m][n] = mfma16(aF[m], bF[n], acc[m][n]);
  }
  const int orow = (lane >> 4) * 4;
  for (int m = 0; m < 4; ++m)
    for (int n = 0; n < 4; ++n)
      for (int i = 0; i < 4; ++i) {
        int k = kt * 128 + wr + m * 16 + orow + i;
        int s = st * 128 + wc + n * 16 + lrow;
        G[((size_t)c * 256 + k) * 256 + s] = (bf16)acc[m][n][i];
      }
}

// ---------------------------------------------------------------------------
// states (bf16) = sum_k (xdt_T * decayO) * B_T
// ---------------------------------------------------------------------------
__global__ __launch_bounds__(256) void states_kernel(
    const bf16* __restrict__ XDT_T, const bf16* __restrict__ BT,
    const float* __restrict__ decayO, bf16* __restrict__ states) {
  const int c = blockIdx.x, h = blockIdx.y;
  __shared__ bf16 Ap[64 * 264];
  __shared__ float sDec[256];
  const int tid = threadIdx.x;
  const int wave = tid >> 6, lane = tid & 63;
  const int lrow = lane & 15, lk = (lane >> 4) * 8;
  sDec[tid] = decayO[(size_t)(c * 64 + h) * 256 + tid];
  __syncthreads();
  {
    int p = tid >> 2, kb = (tid & 3) * 64;
    const bf16* src = XDT_T + (size_t)(h * 64 + p) * 4096 + c * 256 + kb;
    for (int j = 0; j < 8; ++j) {
      bf16x8 v = *(const bf16x8*)(src + j * 8);
      bf16x8 o;
      for (int i = 0; i < 8; ++i) o[i] = (bf16)((float)v[i] * sDec[kb + j * 8 + i]);
      *(bf16x8*)(Ap + p * 264 + kb + j * 8) = o;
    }
  }
  __syncthreads();
  const int nb = wave * 32;
  f32x4 acc[4][2] = {};
  for (int kk = 0; kk < 8; ++kk) {
    bf16x8 aF[4], bF[2];
    for (int m = 0; m < 4; ++m)
      aF[m] = *(const bf16x8*)(Ap + (m * 16 + lrow) * 264 + kk * 32 + lk);
    for (int n = 0; n < 2; ++n)
      bF[n] = *(const bf16x8*)(BT + (size_t)(nb + n * 16 + lrow) * 4096 + c * 256 + kk * 32 + lk);
    for (int m = 0; m < 4; ++m)
      for (int n = 0; n < 2; ++n)
        acc[m][n] = mfma16(aF[m], bF[n], acc[m][n]);
  }
  bf16* st = states + (size_t)(c * 64 + h) * 64 * 128;
  const int orow = (lane >> 4) * 4;
  for (int m = 0; m < 4; ++m)
    for (int n = 0; n < 2; ++n)
      for (int i = 0; i < 4; ++i)
        st[(size_t)(m * 16 + orow + i) * 128 + nb + n * 16 + lrow] = (bf16)acc[m][n][i];
}

// ---------------------------------------------------------------------------
__global__ __launch_bounds__(128) void chunk_rec_kernel(
    const bf16* __restrict__ states, const float* __restrict__ csum,
    bf16* __restrict__ prev) {
  const int h = blockIdx.x, p = blockIdx.y;
  const int n = threadIdx.x;
  size_t base = (size_t)h * 64 * 128 + (size_t)p * 128 + n;
  float run = 0.f;
  for (int c = 0; c < 16; ++c) {
    size_t idx = (size_t)c * 64 * 64 * 128 + base;
    prev[idx] = (bf16)run;
    run = run * __expf(csum[c * 64 + h]) + (float)states[idx];
  }
}

// ---------------------------------------------------------------------------
// Y (bf16) = Y_off + Y_diag per (chunk, head).  (XS*D folded into rmsnorm.)
// ---------------------------------------------------------------------------
__global__ __launch_bounds__(256) void ydiag_kernel(
    const bf16* __restrict__ Cm, const bf16* __restrict__ prev,
    const bf16* __restrict__ Gb, const float* __restrict__ Acs,
    const float* __restrict__ expAcs, const bf16* __restrict__ XDT_T,
    bf16* __restrict__ Yb) {
  const int c = blockIdx.x, h = blockIdx.y;
  __shared__ float sAcs[256];
  __shared__ float sExp[256];
  __shared__ __align__(16) bf16 pv[64 * 136];
  __shared__ __align__(16) bf16 xd[64 * 264];
  const int tid = threadIdx.x;
  const int wave = tid >> 6, lane = tid & 63;
  const int lrow = lane & 15, lk = (lane >> 4) * 8;
  const int wv16 = wave * 16;
  sAcs[tid] = Acs[(size_t)(c * 64 + h) * 256 + tid];
  sExp[tid] = expAcs[(size_t)(c * 64 + h) * 256 + tid];
  {
    int r = tid >> 2, q = (tid & 3) * 32;
    const bf16* src = prev + (size_t)(c * 64 + h) * 8192 + r * 128 + q;
    bf16* dst = pv + r * 136 + q;
    for (int j = 0; j < 4; ++j)
      *(bf16x8*)(dst + j * 8) = *(const bf16x8*)(src + j * 8);
  }
  {
    int r = tid >> 2, q = (tid & 3) * 64;
    const bf16* src = XDT_T + (size_t)(h * 64 + r) * 4096 + c * 256 + q;
    bf16* dst = xd + r * 264 + q;
    for (int j = 0; j < 8; ++j)
      *(bf16x8*)(dst + j * 8) = *(const bf16x8*)(src + j * 8);
  }
  __syncthreads();
  f32x4 acc[4][4] = {};
  bf16x8 aYo[4][4];
#pragma unroll
  for (int kk = 0; kk < 4; ++kk)
#pragma unroll
    for (int m = 0; m < 4; ++m)
      aYo[kk][m] = *(const bf16x8*)(Cm + (size_t)(c * 256 + m * 64 + wv16 + lrow) * 128 + kk * 32 + lk);
#pragma unroll
  for (int kk = 0; kk < 4; ++kk) {
    bf16x8 bF[4];
#pragma unroll
    for (int n = 0; n < 4; ++n)
      bF[n] = *(const bf16x8*)(pv + (n * 16 + lrow) * 136 + kk * 32 + lk);
#pragma unroll
    for (int m = 0; m < 4; ++m)
#pragma unroll
      for (int n = 0; n < 4; ++n)
        acc[m][n] = mfma16(aYo[kk][m], bF[n], acc[m][n]);
  }
  const int orow = (lane >> 4) * 4;
#pragma unroll
  for (int m = 0; m < 4; ++m)
#pragma unroll
    for (int i = 0; i < 4; ++i) {
      float e = sExp[m * 64 + wv16 + orow + i];
      for (int n = 0; n < 4; ++n) acc[m][n][i] *= e;
    }
  const bf16* Gp = Gb + (size_t)c * 65536;
#pragma unroll
  for (int stile = 0; stile < 4; ++stile) {
    const int s0 = stile * 64;
    bf16x8 graw[2][4];
#pragma unroll
    for (int kk = 0; kk < 2; ++kk)
#pragma unroll
      for (int m = 0; m < 4; ++m)
        if (m * 64 + wv16 + 15 >= s0) {
          int row = m * 64 + wv16 + lrow;
          graw[kk][m] = *(const bf16x8*)(Gp + (size_t)row * 256 + s0 + kk * 32 + lk);
        }
    bf16x8 bF[2][4];
#pragma unroll
    for (int kk = 0; kk < 2; ++kk)
#pragma unroll
      for (int n = 0; n < 4; ++n)
        bF[kk][n] = *(const bf16x8*)(xd + (n * 16 + lrow) * 264 + s0 + kk * 32 + lk);
#pragma unroll
    for (int kk = 0; kk < 2; ++kk)
#pragma unroll
      for (int m = 0; m < 4; ++m) {
        if (m * 64 + wv16 + 15 < s0) continue;
        const int row = m * 64 + wv16 + lrow;
        const float ak = sAcs[row];
        bf16x8 af;
#pragma unroll
        for (int j = 0; j < 8; ++j) {
          int s = s0 + kk * 32 + lk + j;
          float v = (float)graw[kk][m][j] * __expf(ak - sAcs[s]);
          if (s > row) v = 0.f;
          af[j] = (bf16)v;
        }
#pragma unroll
        for (int n = 0; n < 4; ++n)
          acc[m][n] = mfma16(af, bF[kk][n], acc[m][n]);
      }
  }
#pragma unroll
  for (int m = 0; m < 4; ++m)
#pragma unroll
    for (int n = 0; n < 4; ++n)
#pragma unroll
      for (int i = 0; i < 4; ++i) {
        int t = c * 256 + m * 64 + wv16 + orow + i;
        int col = h * 64 + n * 16 + lrow;
        Yb[(size_t)t * 4096 + col] = (bf16)acc[m][n][i];
      }
}

// ---------------------------------------------------------------------------
// RMSNorm fused with + XS*D  (bf16 Y input)
// ---------------------------------------------------------------------------
__global__ __launch_bounds__(256) void rmsnorm_kernel(
    const bf16* __restrict__ Yb, const bf16* __restrict__ XS,
    const float* __restrict__ Dp, const float* __restrict__ norm_w,
    bf16* __restrict__ out) {
  const int row = blockIdx.x;
  const bf16x4* y4 = (const bf16x4*)(Yb + (size_t)row * 4096);
  const bf16x4* xs4 = (const bf16x4*)(XS + (size_t)row * 4096);
  float4 v[4];
  float ss = 0.f;
  for (int j = 0; j < 4; ++j) {
    int c4 = threadIdx.x + j * 256;
    bf16x4 yb = y4[c4];
    bf16x4 xs = xs4[c4];
    float d = Dp[(c4 * 4) >> 6];
    float4 y;
    y.x = (float)yb[0] + (float)xs[0] * d;
    y.y = (float)yb[1] + (float)xs[1] * d;
    y.z = (float)yb[2] + (float)xs[2] * d;
    y.w = (float)yb[3] + (float)xs[3] * d;
    v[j] = y;
    ss += y.x * y.x + y.y * y.y + y.z * y.z + y.w * y.w;
  }
  for (int off = 32; off; off >>= 1) ss += __shfl_down(ss, off, 64);
  __shared__ float ws[4];
  if ((threadIdx.x & 63) == 0) ws[threadIdx.x >> 6] = ss;
  __syncthreads();
  float scale = rsqrtf((ws[0] + ws[1] + ws[2] + ws[3]) / 4096.f + 1e-6f);
  for (int j = 0; j < 4; ++j) {
    int col = (threadIdx.x + j * 256) * 4;
    float4 w = *(const float4*)(norm_w + col);
    bf16x4 o = {(bf16)(v[j].x * scale * w.x), (bf16)(v[j].y * scale * w.y),
                (bf16)(v[j].z * scale * w.z), (bf16)(v[j].w * scale * w.w)};
    *(bf16x4*)(out + (size_t)row * 4096 + col) = o;
  }
}

// ---------------------------------------------------------------------------
extern "C" void kernel_launch(void* const* d_in, const int* in_sizes, int n_in,
                              void* d_out, int out_size, void* d_ws, size_t ws_size,
                              hipStream_t stream) {
  const float* x       = (const float*)d_in[0];
  const float* W_in    = (const float*)d_in[1];
  const float* conv_w  = (const float*)d_in[2];
  const float* conv_b  = (const float*)d_in[3];
  const float* dt_bias = (const float*)d_in[4];
  const float* A_log   = (const float*)d_in[5];
  const float* Dp      = (const float*)d_in[6];
  const float* norm_w  = (const float*)d_in[7];
  const float* W_out   = (const float*)d_in[8];

  size_t o = 0;
  char* base = (char*)d_ws;
  auto take = [&](size_t b) {
    char* p = base + o;
    o += (b + 255) & ~(size_t)255;
    return (void*)p;
  };
  bf16*  xb     = (bf16*)take((size_t)4096 * 2048 * 2);    // 16.8 MB
  bf16*  winb   = (bf16*)take((size_t)4608 * 2048 * 2);    // 18.9 MB
  bf16*  xbc    = (bf16*)take((size_t)4096 * 4608 * 2);    // 37.75 MB
  float* dtf    = (float*)take((size_t)4096 * 64 * 4);     // 1 MB
  float* dtg    = (float*)take((size_t)4096 * 64 * 4);
  float* Acs    = (float*)take((size_t)4096 * 64 * 4);
  float* decayO = (float*)take((size_t)4096 * 64 * 4);
  float* expA   = (float*)take((size_t)4096 * 64 * 4);
  float* csum   = (float*)take((size_t)16 * 64 * 4);
  bf16*  XS     = (bf16*)take((size_t)4096 * 4096 * 2);    // 33.6 MB
  bf16*  XDT_T  = (bf16*)take((size_t)4096 * 4096 * 2);    // 33.6 MB
  bf16*  Bm     = (bf16*)take((size_t)4096 * 128 * 2);
  bf16*  BT     = (bf16*)take((size_t)4096 * 128 * 2);
  bf16*  Cm     = (bf16*)take((size_t)4096 * 128 * 2);
  bf16*  Yb     = (bf16*)take((size_t)4096 * 4096 * 2);    // 33.6 MB
  bf16*  prev   = (bf16*)take((size_t)16 * 64 * 64 * 128 * 2);  // 16.8 MB
  bf16*  woutb  = (bf16*)take((size_t)2048 * 4096 * 2);    // 16.8 MB
  // aliases into xbc (dead after conv): Gb | states(bf16)
  bf16*  Gb     = (bf16*)((char*)xbc);                          // 2.10 MB
  bf16*  states = (bf16*)((char*)xbc + (size_t)4194304);        // 16.8 MB
  bf16*  ynorm  = xb;             // xb+winb dead after GEMM1; 33.6 <= 35.7

  // 1) fused casts (x, W_in padded, W_out)
  cast_all_kernel<<<2048, 256, 0, stream>>>(x, xb, W_in, winb, W_out, woutb);
  // 2) GEMM1: xbc = x @ W_in^T (bf16) + f32 dt; 576 blocks (2.25/CU)
  gemm_kernel<64, 2048, true><<<dim3(576, 1), 512, 0, stream>>>(
      xb, winb, xbc, dtf, 4608, 36);
  // 3) dt + per-chunk cumsum
  dt_scan_kernel<<<dim3(16, 64), 256, 0, stream>>>(dtf, dt_bias, A_log, dtg,
                                                   Acs, decayO, expA, csum);
  // 4) conv + silu + layout builds
  conv_kernel<<<dim3(64, 68), 256, 0, stream>>>(xbc, conv_w, conv_b, dtg, XS,
                                                XDT_T, Bm, BT, Cm);
  // 5) G = C @ B^T per chunk (bf16; xbc now dead -> Gb/states live there)
  gmat_kernel<<<dim3(16, 2, 2), 256, 0, stream>>>(Cm, Bm, Gb);
  // 6) intra-chunk states (bf16)
  states_kernel<<<dim3(16, 64), 256, 0, stream>>>(XDT_T, BT, decayO, states);
  // 7) inter-chunk recurrence -> prev (bf16)
  chunk_rec_kernel<<<dim3(64, 64), 128, 0, stream>>>(states, csum, prev);
  // 8) Y = Y_diag + Y_off (bf16)
  ydiag_kernel<<<dim3(16, 64), 256, 0, stream>>>(Cm, prev, Gb, Acs, expA,
                                                 XDT_T, Yb);
  // 9) RMSNorm (fused + XS*D) -> bf16
  rmsnorm_kernel<<<4096, 256, 0, stream>>>(Yb, XS, Dp, norm_w, ynorm);
  // 10) GEMM2: out = ynorm @ W_out^T, f32 DIRECT (no split-K, no add2b);
  //     128^2 tiles, grid 32x16 = 512 blocks = 2/CU
  gemm2_kernel<128, 4096><<<dim3(512, 1), 256, 0, stream>>>(
      ynorm, woutb, (float*)d_out, 2048, 16);
}